// Round 6
// baseline (449.926 us; speedup 1.0000x reference)
//
#include <hip/hip_runtime.h>

#define DIM 1024
#define NHEADS 16
#define HDIM 64
#define BATCH 4
#define SEQ 2048
#define MTOT (BATCH*SEQ)      // 8192 rows
// ATTN_SCALE * log2(e): softmax runs in exp2 domain
#define QSC 0.18033688011112042f
#define KVB 64
#define PSTR_B 144            // P row stride bytes (72 elems)

typedef __bf16 bf16;
typedef __bf16 bf16x8 __attribute__((ext_vector_type(8)));
typedef __bf16 bf16x4 __attribute__((ext_vector_type(4)));
typedef float  f32x4  __attribute__((ext_vector_type(4)));

static __device__ __forceinline__ bf16 f2bf(float f) {
  unsigned u = __builtin_bit_cast(unsigned, f);
  u = (u + 0x7FFFu + ((u >> 16) & 1u)) >> 16;   // RNE
  unsigned short s = (unsigned short)u;
  return __builtin_bit_cast(bf16, s);
}

// async global->LDS, 16B per lane, linear dest (wave base + lane*16)
#define GLD16(gp, lp) __builtin_amdgcn_global_load_lds( \
    (const __attribute__((address_space(1))) void*)(gp), \
    (__attribute__((address_space(3))) void*)(lp), 16, 0, 0)

// ---------------------------------------------------------------- fp32 -> bf16
__global__ __launch_bounds__(256) void k_cvt_x(const float* __restrict__ x,
                                               bf16* __restrict__ xb) {
  size_t i = ((size_t)blockIdx.x * 256 + threadIdx.x) * 4;
  const float4 v = *(const float4*)(x + i);
  bf16x4 o;
  o[0] = f2bf(v.x); o[1] = f2bf(v.y); o[2] = f2bf(v.z); o[3] = f2bf(v.w);
  *(bf16x4*)(xb + i) = o;
}

// ------------------------------------------- W [K=1024][C] -> Wt[C][1024] bf16
__global__ __launch_bounds__(256) void k_prep_w(const float* __restrict__ W,
                                                const float* __restrict__ sc,
                                                bf16* __restrict__ Wt,
                                                int C, int qscale) {
  __shared__ float tile[32][33];
  const int tx = threadIdx.x, ty = threadIdx.y;      // 32 x 8
  const int c0 = blockIdx.x * 32, k0 = blockIdx.y * 32;
#pragma unroll
  for (int j = 0; j < 4; ++j)
    tile[ty + 8*j][tx] = W[(size_t)(k0 + ty + 8*j) * C + (c0 + tx)];
  __syncthreads();
#pragma unroll
  for (int j = 0; j < 4; ++j) {
    int cc = c0 + ty + 8*j;
    float s = sc[cc];
    if (qscale && cc < DIM) s *= QSC;
    Wt[(size_t)cc * DIM + (k0 + tx)] = f2bf(tile[tx][ty + 8*j] * s);
  }
}

// ---------------------------------------------------------------- bf16 GEMM
// MODE 0: scatter qkv -> Q/K [b][h][n][d], V TRANSPOSED -> Vt [b][h][d][n]
// MODE 1: out fp32 = acc + g2*bp  (g2 folded in Bt)
template<int MODE>
__global__ __launch_bounds__(256) void k_gemm(const bf16* __restrict__ A,
                                              const bf16* __restrict__ Bt,
                                              int nblk,
                                              float* __restrict__ outp,
                                              const float* __restrict__ g2,
                                              const float* __restrict__ bp,
                                              bf16* __restrict__ Qb,
                                              bf16* __restrict__ Kb,
                                              bf16* __restrict__ Vb) {
  __shared__ bf16 Als[128*32];
  __shared__ bf16 Bls[128*32];
  const int b0 = blockIdx.x;
  const int bswz = (b0 & 7) * ((int)gridDim.x >> 3) + (b0 >> 3);  // XCD chunk
  const int bm = bswz / nblk, bn = bswz % nblk;
  const int t = threadIdx.x;
  const int lane = t & 63, wave = t >> 6;
  const int c = lane & 15, g = lane >> 4;
  const int wm = (wave >> 1) * 64, wn = (wave & 1) * 64;
  const int srow = t >> 2, schunk = t & 3;           // staging map: 64B rows
  const bf16* Ab = A  + (size_t)(bm*128) * DIM;
  const bf16* Bb = Bt + (size_t)(bn*128) * DIM;
  f32x4 acc[4][4] = {};
  for (int k0 = 0; k0 < DIM; k0 += 32) {
    __syncthreads();
#pragma unroll
    for (int i = 0; i < 2; ++i) {
      GLD16(Ab + (size_t)(i*64 + srow)*DIM + k0 + schunk*8,
            (char*)Als + i*4096 + t*16);
      GLD16(Bb + (size_t)(i*64 + srow)*DIM + k0 + schunk*8,
            (char*)Bls + i*4096 + t*16);
    }
    __syncthreads();
    bf16x8 a[4], b[4];
#pragma unroll
    for (int m = 0; m < 4; ++m)
      a[m] = *(const bf16x8*)&Als[(wm + m*16 + c)*32 + g*8];
#pragma unroll
    for (int n = 0; n < 4; ++n)
      b[n] = *(const bf16x8*)&Bls[(wn + n*16 + c)*32 + g*8];
#pragma unroll
    for (int m = 0; m < 4; ++m)
#pragma unroll
      for (int n = 0; n < 4; ++n)
        acc[m][n] = __builtin_amdgcn_mfma_f32_16x16x32_bf16(a[m], b[n], acc[m][n], 0, 0, 0);
  }
  const int cb = bn*128 + wn, rb = bm*128 + wm;
  if (MODE == 0) {
    const int which = (bn*128) >> 10;                 // 0=Q 1=K 2=V
    if (which < 2) {
      bf16* dst = which == 0 ? Qb : Kb;
#pragma unroll
      for (int n = 0; n < 4; ++n) {
        const int colg = cb + n*16 + c;
        const int h = (colg >> 6) & 15, d = colg & 63;
        const size_t hd = (size_t)h * (SEQ*HDIM) + d;
#pragma unroll
        for (int m = 0; m < 4; ++m)
#pragma unroll
          for (int r = 0; r < 4; ++r) {
            const int row = rb + m*16 + 4*g + r;
            const int bb = row >> 11, nt = row & 2047;
            dst[(size_t)bb * (NHEADS*SEQ*HDIM) + hd + (size_t)nt * HDIM] = (bf16)acc[m][n][r];
          }
      }
    } else {
      // V transposed: Vt[b][h][d][n] ; 4 consecutive tokens -> bf16x4 store
#pragma unroll
      for (int n = 0; n < 4; ++n) {
        const int colg = cb + n*16 + c;
        const int h = (colg >> 6) & 15, d = colg & 63;
#pragma unroll
        for (int m = 0; m < 4; ++m) {
          const int row0 = rb + m*16 + 4*g;
          const int bb = row0 >> 11, nt = row0 & 2047;
          bf16x4 pk;
          pk[0] = (bf16)acc[m][n][0]; pk[1] = (bf16)acc[m][n][1];
          pk[2] = (bf16)acc[m][n][2]; pk[3] = (bf16)acc[m][n][3];
          *(bf16x4*)(Vb + ((size_t)(bb*NHEADS + h)*HDIM + d)*SEQ + nt) = pk;
        }
      }
    }
  } else {
#pragma unroll
    for (int n = 0; n < 4; ++n) {
      const int col = cb + n*16 + c;
      const float bias = g2[col] * bp[col];
#pragma unroll
      for (int m = 0; m < 4; ++m)
#pragma unroll
        for (int r = 0; r < 4; ++r) {
          const int row = rb + m*16 + 4*g + r;
          outp[(size_t)row * DIM + col] = acc[m][n][r] + bias;
        }
    }
  }
}

// ---------------------------------------------------------------- attention
// grid 1024 = (B*H=64) x (N/128=16), XCD-chunked. 4 waves x 32 q-rows. KVB=64.
// K LDS [64kv][64d], V LDS [64d][64kv] (from pre-transposed Vt), both staged by
// global_load_lds with inverse-XOR source so reads at byte^((row&7)<<4) are
// bank-uniform. P LDS per-wave [32q][72] stride 144B, XOR ((row>>2)&3)<<5.
// PV computed as O^T = mfma(V^T-frag, P-frag): all operands ds_read_b128.
__global__ __launch_bounds__(256) void k_attn(const bf16* __restrict__ Q,
                                              const bf16* __restrict__ K,
                                              const bf16* __restrict__ Vt,
                                              bf16* __restrict__ O) {
  __shared__ __align__(16) char Kls[KVB*128];        // 8 KB
  __shared__ __align__(16) char Vls[64*KVB*2];       // 8 KB
  __shared__ __align__(16) char Pls[4][32*PSTR_B];   // 18 KB
  const int b0 = blockIdx.x;
  const int bid = (b0 & 7) * 128 + (b0 >> 3);        // same-head blocks -> same XCD
  const int qt = bid & 15, bh = bid >> 4;
  const int t = threadIdx.x, wave = t >> 6, lane = t & 63;
  const int c = lane & 15, g = lane >> 4;
  const int g32 = g << 5;
  const int csw = (c & 7) << 4;                      // K/V read swizzle
  const int psw = (c >> 2) << 5;                     // P read swizzle
  char* Pw = Pls[wave];
  const bf16* Qp = Q + ((size_t)bh * SEQ + qt*128) * HDIM;
  const bf16* Kp = K + (size_t)bh * SEQ * HDIM;
  const bf16* Vh = Vt + (size_t)bh * HDIM * SEQ;     // [d][n]
  // Q fragments (A-operand: row=lane&15=q, k=8g+j=d)
  bf16x8 qf[2][2];
#pragma unroll
  for (int m = 0; m < 2; ++m)
#pragma unroll
    for (int kk = 0; kk < 2; ++kk)
      qf[m][kk] = *(const bf16x8*)(Qp + (size_t)(wave*32 + m*16 + c)*HDIM + kk*32 + g*8);
  f32x4 oacc[2][4] = {};
  float rm[2][4], rl[2][4];
#pragma unroll
  for (int m = 0; m < 2; ++m)
#pragma unroll
    for (int r = 0; r < 4; ++r) { rm[m][r] = -1e30f; rl[m][r] = 0.f; }

  for (int kv0 = 0; kv0 < SEQ; kv0 += KVB) {
    __syncthreads();                                  // prior tile reads done
    // stage K tile [64][64] and V tile [64][64], 2 GLD16 rounds each
#pragma unroll
    for (int i = 0; i < 2; ++i) {
      const int id = i*256 + t, row = id >> 3, cbk = id & 7;
      GLD16(Kp + (size_t)(kv0 + row)*HDIM + 8*(cbk ^ (row & 7)), Kls + id*16);
    }
#pragma unroll
    for (int i = 0; i < 2; ++i) {
      const int id = i*256 + t, row = id >> 3, cbk = id & 7;
      GLD16(Vh + (size_t)row*SEQ + kv0 + 8*(cbk ^ (row & 7)), Vls + id*16);
    }
    __syncthreads();                                  // drain -> staged visible
    // S = Q K^T : s[m][n] rows q=4g+r, cols kv=n*16+c
    f32x4 s[2][4] = {};
#pragma unroll
    for (int kk = 0; kk < 2; ++kk)
#pragma unroll
      for (int n = 0; n < 4; ++n) {
        const bf16x8 kb = *(const bf16x8*)(Kls + (n*16 + c)*128 + ((kk*64 + 16*g) ^ csw));
#pragma unroll
        for (int m = 0; m < 2; ++m)
          s[m][n] = __builtin_amdgcn_mfma_f32_16x16x32_bf16(qf[m][kk], kb, s[m][n], 0, 0, 0);
      }
    // online softmax (exp2 domain; scale folded into Wq)
#pragma unroll
    for (int m = 0; m < 2; ++m) {
      float mnew[4], alpha[4];
#pragma unroll
      for (int r = 0; r < 4; ++r) {
        float pm = fmaxf(fmaxf(s[m][0][r], s[m][1][r]), fmaxf(s[m][2][r], s[m][3][r]));
#pragma unroll
        for (int off = 1; off < 16; off <<= 1) pm = fmaxf(pm, __shfl_xor(pm, off, 16));
        mnew[r] = fmaxf(rm[m][r], pm);
        alpha[r] = exp2f(rm[m][r] - mnew[r]);
        rm[m][r] = mnew[r];
      }
      float psum[4] = {0.f, 0.f, 0.f, 0.f};
#pragma unroll
      for (int n = 0; n < 4; ++n)
#pragma unroll
        for (int r = 0; r < 4; ++r) {
          const float p = exp2f(s[m][n][r] - mnew[r]);
          psum[r] += p;
          *(bf16*)(Pw + (m*16 + 4*g + r)*PSTR_B + (((n*16 + c)*2) ^ g32)) = (bf16)p;
        }
#pragma unroll
      for (int r = 0; r < 4; ++r) {
#pragma unroll
        for (int off = 1; off < 16; off <<= 1) psum[r] += __shfl_xor(psum[r], off, 16);
        rl[m][r] = rl[m][r]*alpha[r] + psum[r];
      }
      // broadcast alpha to q-columns (O^T layout: lane's q = m*16+c) and rescale
      float asel = (c & 2) ? ((c & 1) ? alpha[3] : alpha[2])
                           : ((c & 1) ? alpha[1] : alpha[0]);
      float aq = __shfl(asel, ((c >> 2) << 4) + (c & 3), 64);
#pragma unroll
      for (int df = 0; df < 4; ++df) {
        oacc[m][df][0] *= aq; oacc[m][df][1] *= aq;
        oacc[m][df][2] *= aq; oacc[m][df][3] *= aq;
      }
    }
    // O^T += V^T P^T : A-frag = V^T rows d, B-frag = P rows q (kv contiguous)
#pragma unroll
    for (int kf = 0; kf < 2; ++kf) {
      bf16x8 pbm[2];
#pragma unroll
      for (int m = 0; m < 2; ++m)
        pbm[m] = *(const bf16x8*)(Pw + (m*16 + c)*PSTR_B + ((kf*64 + 16*g) ^ psw));
#pragma unroll
      for (int df = 0; df < 4; ++df) {
        const bf16x8 va = *(const bf16x8*)(Vls + (df*16 + c)*128 + ((kf*64 + 16*g) ^ csw));
#pragma unroll
        for (int m = 0; m < 2; ++m)
          oacc[m][df] = __builtin_amdgcn_mfma_f32_16x16x32_bf16(va, pbm[m], oacc[m][df], 0, 0, 0);
      }
    }
  }
  // epilogue: O^T[d][q] -> O[b][q][h*64+d] bf16 (token-major for proj GEMM)
  const int b = bh >> 4, h = bh & 15;
#pragma unroll
  for (int m = 0; m < 2; ++m) {
    float lsel = (c & 2) ? ((c & 1) ? rl[m][3] : rl[m][2])
                         : ((c & 1) ? rl[m][1] : rl[m][0]);
    float lq = __shfl(lsel, ((c >> 2) << 4) + (c & 3), 64);
    const float inv = 1.0f / lq;
    const int qg = qt*128 + wave*32 + m*16 + c;
    bf16* orow = O + ((size_t)b*SEQ + qg)*DIM + h*HDIM;
#pragma unroll
    for (int df = 0; df < 4; ++df)
#pragma unroll
      for (int r = 0; r < 4; ++r)
        orow[df*16 + 4*g + r] = (bf16)(oacc[m][df][r] * inv);
  }
}

// ---------------------------------------------------------------- launch
extern "C" void kernel_launch(void* const* d_in, const int* in_sizes, int n_in,
                              void* d_out, int out_size, void* d_ws, size_t ws_size,
                              hipStream_t stream) {
  const float* x    = (const float*)d_in[0];
  const float* Wqkv = (const float*)d_in[1];
  const float* g1   = (const float*)d_in[2];
  const float* Wp   = (const float*)d_in[3];
  const float* bp   = (const float*)d_in[4];
  const float* g2   = (const float*)d_in[5];
  float* out = (float*)d_out;
  char* ws = (char*)d_ws;
  bf16* xb  = (bf16*)ws;                       // 16 MiB [8192][1024]; reused as O
  bf16* Wqt = (bf16*)(ws + (16u<<20));         //  6 MiB [3072][1024]
  bf16* Wpt = (bf16*)(ws + (22u<<20));         //  2 MiB [1024][1024]
  bf16* Qb  = (bf16*)(ws + (24u<<20));         // 16 MiB [b][h][n][d]
  bf16* Kb  = (bf16*)(ws + (40u<<20));         // 16 MiB [b][h][n][d]
  bf16* Vb  = (bf16*)(ws + (56u<<20));         // 16 MiB [b][h][d][n]  (transposed)

  k_cvt_x<<<(MTOT*DIM)/1024, 256, 0, stream>>>(x, xb);
  k_prep_w<<<dim3(96, 32), dim3(32, 8), 0, stream>>>(Wqkv, g1, Wqt, 3*DIM, 1);
  k_prep_w<<<dim3(32, 32), dim3(32, 8), 0, stream>>>(Wp, g2, Wpt, DIM, 0);
  k_gemm<0><<<64*24, 256, 0, stream>>>(xb, Wqt, 24, nullptr, nullptr, nullptr, Qb, Kb, Vb);
  k_attn<<<64*16, 256, 0, stream>>>(Qb, Kb, Vb, xb);
  k_gemm<1><<<64*8, 256, 0, stream>>>(xb, Wpt, 8, out, g2, bp, nullptr, nullptr, nullptr);
}

// Round 7
// 356.828 us; speedup vs baseline: 1.2609x; 1.2609x over previous
//
#include <hip/hip_runtime.h>

#define DIM 1024
#define NHEADS 16
#define HDIM 64
#define BATCH 4
#define SEQ 2048
#define MTOT (BATCH*SEQ)      // 8192 rows
// ATTN_SCALE * log2(e): softmax runs in exp2 domain
#define QSC 0.18033688011112042f
#define KVB 64
#define PSTR_B 144            // P row stride bytes (72 elems)
#define DEFER_THR 8.0f

typedef __bf16 bf16;
typedef __bf16 bf16x8 __attribute__((ext_vector_type(8)));
typedef __bf16 bf16x4 __attribute__((ext_vector_type(4)));
typedef float  f32x4  __attribute__((ext_vector_type(4)));

static __device__ __forceinline__ bf16 f2bf(float f) {
  unsigned u = __builtin_bit_cast(unsigned, f);
  u = (u + 0x7FFFu + ((u >> 16) & 1u)) >> 16;   // RNE
  unsigned short s = (unsigned short)u;
  return __builtin_bit_cast(bf16, s);
}

// async global->LDS, 16B per lane, linear dest (wave base + lane*16)
#define GLD16(gp, lp) __builtin_amdgcn_global_load_lds( \
    (const __attribute__((address_space(1))) void*)(gp), \
    (__attribute__((address_space(3))) void*)(lp), 16, 0, 0)

// ---------------------------------------------------------------- fp32 -> bf16
__global__ __launch_bounds__(256) void k_cvt_x(const float* __restrict__ x,
                                               bf16* __restrict__ xb) {
  size_t i = ((size_t)blockIdx.x * 256 + threadIdx.x) * 4;
  const float4 v = *(const float4*)(x + i);
  bf16x4 o;
  o[0] = f2bf(v.x); o[1] = f2bf(v.y); o[2] = f2bf(v.z); o[3] = f2bf(v.w);
  *(bf16x4*)(xb + i) = o;
}

// ------------------------------------------- W [K=1024][C] -> Wt[C][1024] bf16
__global__ __launch_bounds__(256) void k_prep_w(const float* __restrict__ W,
                                                const float* __restrict__ sc,
                                                bf16* __restrict__ Wt,
                                                int C, int qscale) {
  __shared__ float tile[32][33];
  const int tx = threadIdx.x, ty = threadIdx.y;      // 32 x 8
  const int c0 = blockIdx.x * 32, k0 = blockIdx.y * 32;
#pragma unroll
  for (int j = 0; j < 4; ++j)
    tile[ty + 8*j][tx] = W[(size_t)(k0 + ty + 8*j) * C + (c0 + tx)];
  __syncthreads();
#pragma unroll
  for (int j = 0; j < 4; ++j) {
    int cc = c0 + ty + 8*j;
    float s = sc[cc];
    if (qscale && cc < DIM) s *= QSC;
    Wt[(size_t)cc * DIM + (k0 + tx)] = f2bf(tile[tx][ty + 8*j] * s);
  }
}

// ---------------------------------------------------------------- bf16 GEMM
// MODE 0: scatter qkv -> Q/K [b][h][n][d], V TRANSPOSED -> Vt [b][h][d][n]
// MODE 1: out fp32 = acc + g2*bp  (g2 folded in Bt)
template<int MODE>
__global__ __launch_bounds__(256) void k_gemm(const bf16* __restrict__ A,
                                              const bf16* __restrict__ Bt,
                                              int nblk,
                                              float* __restrict__ outp,
                                              const float* __restrict__ g2,
                                              const float* __restrict__ bp,
                                              bf16* __restrict__ Qb,
                                              bf16* __restrict__ Kb,
                                              bf16* __restrict__ Vb) {
  __shared__ bf16 Als[128*32];
  __shared__ bf16 Bls[128*32];
  const int b0 = blockIdx.x;
  const int bswz = (b0 & 7) * ((int)gridDim.x >> 3) + (b0 >> 3);  // XCD chunk
  const int bm = bswz / nblk, bn = bswz % nblk;
  const int t = threadIdx.x;
  const int lane = t & 63, wave = t >> 6;
  const int c = lane & 15, g = lane >> 4;
  const int wm = (wave >> 1) * 64, wn = (wave & 1) * 64;
  const int srow = t >> 2, schunk = t & 3;           // staging map: 64B rows
  const bf16* Ab = A  + (size_t)(bm*128) * DIM;
  const bf16* Bb = Bt + (size_t)(bn*128) * DIM;
  f32x4 acc[4][4] = {};
  for (int k0 = 0; k0 < DIM; k0 += 32) {
    __syncthreads();
#pragma unroll
    for (int i = 0; i < 2; ++i) {
      GLD16(Ab + (size_t)(i*64 + srow)*DIM + k0 + schunk*8,
            (char*)Als + i*4096 + t*16);
      GLD16(Bb + (size_t)(i*64 + srow)*DIM + k0 + schunk*8,
            (char*)Bls + i*4096 + t*16);
    }
    __syncthreads();
    bf16x8 a[4], b[4];
#pragma unroll
    for (int m = 0; m < 4; ++m)
      a[m] = *(const bf16x8*)&Als[(wm + m*16 + c)*32 + g*8];
#pragma unroll
    for (int n = 0; n < 4; ++n)
      b[n] = *(const bf16x8*)&Bls[(wn + n*16 + c)*32 + g*8];
#pragma unroll
    for (int m = 0; m < 4; ++m)
#pragma unroll
      for (int n = 0; n < 4; ++n)
        acc[m][n] = __builtin_amdgcn_mfma_f32_16x16x32_bf16(a[m], b[n], acc[m][n], 0, 0, 0);
  }
  const int cb = bn*128 + wn, rb = bm*128 + wm;
  if (MODE == 0) {
    const int which = (bn*128) >> 10;                 // 0=Q 1=K 2=V
    if (which < 2) {
      bf16* dst = which == 0 ? Qb : Kb;
#pragma unroll
      for (int n = 0; n < 4; ++n) {
        const int colg = cb + n*16 + c;
        const int h = (colg >> 6) & 15, d = colg & 63;
        const size_t hd = (size_t)h * (SEQ*HDIM) + d;
#pragma unroll
        for (int m = 0; m < 4; ++m)
#pragma unroll
          for (int r = 0; r < 4; ++r) {
            const int row = rb + m*16 + 4*g + r;
            const int bb = row >> 11, nt = row & 2047;
            dst[(size_t)bb * (NHEADS*SEQ*HDIM) + hd + (size_t)nt * HDIM] = (bf16)acc[m][n][r];
          }
      }
    } else {
      // V transposed: Vt[b][h][d][n] ; 4 consecutive tokens -> bf16x4 store
#pragma unroll
      for (int n = 0; n < 4; ++n) {
        const int colg = cb + n*16 + c;
        const int h = (colg >> 6) & 15, d = colg & 63;
#pragma unroll
        for (int m = 0; m < 4; ++m) {
          const int row0 = rb + m*16 + 4*g;
          const int bb = row0 >> 11, nt = row0 & 2047;
          bf16x4 pk;
          pk[0] = (bf16)acc[m][n][0]; pk[1] = (bf16)acc[m][n][1];
          pk[2] = (bf16)acc[m][n][2]; pk[3] = (bf16)acc[m][n][3];
          *(bf16x4*)(Vb + ((size_t)(bb*NHEADS + h)*HDIM + d)*SEQ + nt) = pk;
        }
      }
    }
  } else {
#pragma unroll
    for (int n = 0; n < 4; ++n) {
      const int col = cb + n*16 + c;
      const float bias = g2[col] * bp[col];
#pragma unroll
      for (int m = 0; m < 4; ++m)
#pragma unroll
        for (int r = 0; r < 4; ++r) {
          const int row = rb + m*16 + 4*g + r;
          outp[(size_t)row * DIM + col] = acc[m][n][r] + bias;
        }
    }
  }
}

// ---------------------------------------------------------------- attention
// grid 1024, XCD-chunked. 4 waves x 32 q-rows. KVB=64.
// K LDS [64kv][64d]; V LDS [80d][64kv]: rows 0-63 staged from pre-transposed
// Vt, row 64 = ones (l accumulates as O^T row 64 via MFMA), rows 65-79 = 0.
// Softmax: ballot-gated defer-max (THR=8) — full shfl reduce + rescale only
// when a tile's per-thread max exceeds running max + THR (tile 0 always).
__global__ __launch_bounds__(256) void k_attn(const bf16* __restrict__ Q,
                                              const bf16* __restrict__ K,
                                              const bf16* __restrict__ Vt,
                                              bf16* __restrict__ O) {
  __shared__ __align__(16) char Kls[KVB*128];        //  8 KB
  __shared__ __align__(16) char Vls[80*128];         // 10 KB (incl ones block)
  __shared__ __align__(16) char Pls[4][32*PSTR_B];   // 18 KB
  const int b0 = blockIdx.x;
  const int bid = (b0 & 7) * 128 + (b0 >> 3);        // same-head blocks -> same XCD
  const int qt = bid & 15, bh = bid >> 4;
  const int t = threadIdx.x, wave = t >> 6, lane = t & 63;
  const int c = lane & 15, g = lane >> 4;
  const int g32 = g << 5;
  const int csw = (c & 7) << 4;                      // K/V read swizzle
  const int psw = (c >> 2) << 5;                     // P read swizzle
  char* Pw = Pls[wave];
  const bf16* Qp = Q + ((size_t)bh * SEQ + qt*128) * HDIM;
  const bf16* Kp = K + (size_t)bh * SEQ * HDIM;
  const bf16* Vh = Vt + (size_t)bh * HDIM * SEQ;     // [d][n]
  // init V^T rows 64..79: row 64 = 1.0 (l-row), rest 0. 2048B = 256 thr x 8B.
  {
    bf16 fill = (t*8 < 128) ? f2bf(1.0f) : (bf16)0.f;
    bf16x4 iv; iv[0] = fill; iv[1] = fill; iv[2] = fill; iv[3] = fill;
    *(bf16x4*)(Vls + 64*128 + t*8) = iv;
  }
  // Q fragments (A-operand: row=lane&15=q, k=8g+j=d)
  bf16x8 qf[2][2];
#pragma unroll
  for (int m = 0; m < 2; ++m)
#pragma unroll
    for (int kk = 0; kk < 2; ++kk)
      qf[m][kk] = *(const bf16x8*)(Qp + (size_t)(wave*32 + m*16 + c)*HDIM + kk*32 + g*8);
  f32x4 oacc[2][5] = {};                             // df=4 holds l (row 64)
  float rm[2][4];
#pragma unroll
  for (int m = 0; m < 2; ++m)
#pragma unroll
    for (int r = 0; r < 4; ++r) rm[m][r] = -1e30f;

  for (int kv0 = 0; kv0 < SEQ; kv0 += KVB) {
    __syncthreads();                                  // prior tile reads done
#pragma unroll
    for (int i = 0; i < 2; ++i) {
      const int id = i*256 + t, row = id >> 3, cbk = id & 7;
      GLD16(Kp + (size_t)(kv0 + row)*HDIM + 8*(cbk ^ (row & 7)), Kls + id*16);
    }
#pragma unroll
    for (int i = 0; i < 2; ++i) {
      const int id = i*256 + t, row = id >> 3, cbk = id & 7;
      GLD16(Vh + (size_t)row*SEQ + kv0 + 8*(cbk ^ (row & 7)), Vls + id*16);
    }
    __syncthreads();                                  // drain -> staged visible
    // S = Q K^T : s[m][n] rows q=4g+r, cols kv=n*16+c
    f32x4 s[2][4] = {};
#pragma unroll
    for (int kk = 0; kk < 2; ++kk)
#pragma unroll
      for (int n = 0; n < 4; ++n) {
        const bf16x8 kb = *(const bf16x8*)(Kls + (n*16 + c)*128 + ((kk*64 + 16*g) ^ csw));
#pragma unroll
        for (int m = 0; m < 2; ++m)
          s[m][n] = __builtin_amdgcn_mfma_f32_16x16x32_bf16(qf[m][kk], kb, s[m][n], 0, 0, 0);
      }
    // ------- softmax: cheap per-thread bound check, rare full reduce -------
    float pm[2][4];
    bool allok = true;
#pragma unroll
    for (int m = 0; m < 2; ++m)
#pragma unroll
      for (int r = 0; r < 4; ++r) {
        pm[m][r] = fmaxf(fmaxf(s[m][0][r], s[m][1][r]), fmaxf(s[m][2][r], s[m][3][r]));
        allok = allok && (pm[m][r] <= rm[m][r] + DEFER_THR);
      }
    if (kv0 == 0 || !__all((int)allok)) {            // wave-uniform branch
#pragma unroll
      for (int m = 0; m < 2; ++m) {
        float alpha[4];
#pragma unroll
        for (int r = 0; r < 4; ++r) {
          float v = pm[m][r];
#pragma unroll
          for (int off = 1; off < 16; off <<= 1) v = fmaxf(v, __shfl_xor(v, off, 16));
          const float mnew = fmaxf(rm[m][r], v);
          alpha[r] = exp2f(rm[m][r] - mnew);
          rm[m][r] = mnew;
        }
        // broadcast alpha to q-columns (lane's oacc col q = m*16+c)
        float asel = (c & 2) ? ((c & 1) ? alpha[3] : alpha[2])
                             : ((c & 1) ? alpha[1] : alpha[0]);
        float aq = __shfl(asel, ((c >> 2) << 4) + (c & 3), 64);
#pragma unroll
        for (int df = 0; df < 5; ++df) {             // incl l-row
          oacc[m][df][0] *= aq; oacc[m][df][1] *= aq;
          oacc[m][df][2] *= aq; oacc[m][df][3] *= aq;
        }
      }
    }
    // P = exp2(s - rm), store to Pls (l-sum comes free via ones-row MFMA)
#pragma unroll
    for (int m = 0; m < 2; ++m)
#pragma unroll
      for (int n = 0; n < 4; ++n)
#pragma unroll
        for (int r = 0; r < 4; ++r) {
          const float p = exp2f(s[m][n][r] - rm[m][r]);
          *(bf16*)(Pw + (m*16 + 4*g + r)*PSTR_B + (((n*16 + c)*2) ^ g32)) = (bf16)p;
        }
    // O^T += V^T P^T (df=4 block: ones-row -> l in O^T row 64)
#pragma unroll
    for (int kf = 0; kf < 2; ++kf) {
      bf16x8 pbm[2];
#pragma unroll
      for (int m = 0; m < 2; ++m)
        pbm[m] = *(const bf16x8*)(Pw + (m*16 + c)*PSTR_B + ((kf*64 + 16*g) ^ psw));
#pragma unroll
      for (int df = 0; df < 5; ++df) {
        const bf16x8 va = *(const bf16x8*)(Vls + (df*16 + c)*128 + ((kf*64 + 16*g) ^ csw));
#pragma unroll
        for (int m = 0; m < 2; ++m)
          oacc[m][df] = __builtin_amdgcn_mfma_f32_16x16x32_bf16(va, pbm[m], oacc[m][df], 0, 0, 0);
      }
    }
  }
  // epilogue: O^T[d][q] -> O[b][q][h*64+d] bf16. l = oacc[m][4][0] on g==0
  // lanes (d-row 64); lane c (index<16) holds col q=m*16+c -> shfl from lane c.
  const int b = bh >> 4, h = bh & 15;
#pragma unroll
  for (int m = 0; m < 2; ++m) {
    const float lq = __shfl(oacc[m][4][0], c, 64);
    const float inv = 1.0f / lq;
    const int qg = qt*128 + wave*32 + m*16 + c;
    bf16* orow = O + ((size_t)b*SEQ + qg)*DIM + h*HDIM;
#pragma unroll
    for (int df = 0; df < 4; ++df)
#pragma unroll
      for (int r = 0; r < 4; ++r)
        orow[df*16 + 4*g + r] = (bf16)(oacc[m][df][r] * inv);
  }
}

// ---------------------------------------------------------------- launch
extern "C" void kernel_launch(void* const* d_in, const int* in_sizes, int n_in,
                              void* d_out, int out_size, void* d_ws, size_t ws_size,
                              hipStream_t stream) {
  const float* x    = (const float*)d_in[0];
  const float* Wqkv = (const float*)d_in[1];
  const float* g1   = (const float*)d_in[2];
  const float* Wp   = (const float*)d_in[3];
  const float* bp   = (const float*)d_in[4];
  const float* g2   = (const float*)d_in[5];
  float* out = (float*)d_out;
  char* ws = (char*)d_ws;
  bf16* xb  = (bf16*)ws;                       // 16 MiB [8192][1024]; reused as O
  bf16* Wqt = (bf16*)(ws + (16u<<20));         //  6 MiB [3072][1024]
  bf16* Wpt = (bf16*)(ws + (22u<<20));         //  2 MiB [1024][1024]
  bf16* Qb  = (bf16*)(ws + (24u<<20));         // 16 MiB [b][h][n][d]
  bf16* Kb  = (bf16*)(ws + (40u<<20));         // 16 MiB [b][h][n][d]
  bf16* Vb  = (bf16*)(ws + (56u<<20));         // 16 MiB [b][h][d][n]  (transposed)

  k_cvt_x<<<(MTOT*DIM)/1024, 256, 0, stream>>>(x, xb);
  k_prep_w<<<dim3(96, 32), dim3(32, 8), 0, stream>>>(Wqkv, g1, Wqt, 3*DIM, 1);
  k_prep_w<<<dim3(32, 32), dim3(32, 8), 0, stream>>>(Wp, g2, Wpt, DIM, 0);
  k_gemm<0><<<64*24, 256, 0, stream>>>(xb, Wqt, 24, nullptr, nullptr, nullptr, Qb, Kb, Vb);
  k_attn<<<64*16, 256, 0, stream>>>(Qb, Kb, Vb, xb);
  k_gemm<1><<<64*8, 256, 0, stream>>>(xb, Wpt, 8, out, g2, bp, nullptr, nullptr, nullptr);
}

// Round 10
// 279.264 us; speedup vs baseline: 1.6111x; 1.2777x over previous
//
#include <hip/hip_runtime.h>

#define DIM 1024
#define NHEADS 16
#define HDIM 64
#define BATCH 4
#define SEQ 2048
#define MTOT (BATCH*SEQ)      // 8192 rows
// ATTN_SCALE * log2(e): softmax runs in exp2 domain
#define QSC 0.18033688011112042f
#define KVB 64
#define NT (SEQ/KVB)
#define PSTR_B 144            // P row stride bytes (72 elems)
#define DEFER_THR 8.0f

typedef __bf16 bf16;
typedef __bf16 bf16x8 __attribute__((ext_vector_type(8)));
typedef __bf16 bf16x4 __attribute__((ext_vector_type(4)));
typedef float  f32x4  __attribute__((ext_vector_type(4)));

static __device__ __forceinline__ bf16 f2bf(float f) {
  unsigned u = __builtin_bit_cast(unsigned, f);
  u = (u + 0x7FFFu + ((u >> 16) & 1u)) >> 16;   // RNE
  unsigned short s = (unsigned short)u;
  return __builtin_bit_cast(bf16, s);
}

static __device__ __forceinline__ float exp2g(float x) {
#if __has_builtin(__builtin_amdgcn_exp2f)
  return __builtin_amdgcn_exp2f(x);            // single v_exp_f32
#else
  float r; asm("v_exp_f32 %0, %1" : "=v"(r) : "v"(x)); return r;
#endif
}

// async global->LDS, 16B per lane, linear dest (wave base + lane*16)
#define GLD16(gp, lp) __builtin_amdgcn_global_load_lds( \
    (const __attribute__((address_space(1))) void*)(gp), \
    (__attribute__((address_space(3))) void*)(lp), 16, 0, 0)

// ---------------------------------------------------------------- fp32 -> bf16
__global__ __launch_bounds__(256) void k_cvt_x(const float* __restrict__ x,
                                               bf16* __restrict__ xb) {
  size_t i = ((size_t)blockIdx.x * 256 + threadIdx.x) * 4;
  const float4 v = *(const float4*)(x + i);
  bf16x4 o;
  o[0] = f2bf(v.x); o[1] = f2bf(v.y); o[2] = f2bf(v.z); o[3] = f2bf(v.w);
  *(bf16x4*)(xb + i) = o;
}

// ------------------------------------------- W [K=1024][C] -> Wt[C][1024] bf16
__global__ __launch_bounds__(256) void k_prep_w(const float* __restrict__ W,
                                                const float* __restrict__ sc,
                                                bf16* __restrict__ Wt,
                                                int C, int qscale) {
  __shared__ float tile[32][33];
  const int tx = threadIdx.x, ty = threadIdx.y;      // 32 x 8
  const int c0 = blockIdx.x * 32, k0 = blockIdx.y * 32;
#pragma unroll
  for (int j = 0; j < 4; ++j)
    tile[ty + 8*j][tx] = W[(size_t)(k0 + ty + 8*j) * C + (c0 + tx)];
  __syncthreads();
#pragma unroll
  for (int j = 0; j < 4; ++j) {
    int cc = c0 + ty + 8*j;
    float s = sc[cc];
    if (qscale && cc < DIM) s *= QSC;
    Wt[(size_t)cc * DIM + (k0 + tx)] = f2bf(tile[tx][ty + 8*j] * s);
  }
}

// ---------------------------------------------------------------- bf16 GEMM
// MODE 0: scatter qkv -> Q/K [b][h][n][d], V TRANSPOSED -> Vt [b][h][d][n]
// MODE 1: out fp32 = acc + g2*bp  (g2 folded in Bt)
template<int MODE>
__global__ __launch_bounds__(256) void k_gemm(const bf16* __restrict__ A,
                                              const bf16* __restrict__ Bt,
                                              int nblk,
                                              float* __restrict__ outp,
                                              const float* __restrict__ g2,
                                              const float* __restrict__ bp,
                                              bf16* __restrict__ Qb,
                                              bf16* __restrict__ Kb,
                                              bf16* __restrict__ Vb) {
  __shared__ bf16 Als[128*32];
  __shared__ bf16 Bls[128*32];
  const int b0 = blockIdx.x;
  const int bswz = (b0 & 7) * ((int)gridDim.x >> 3) + (b0 >> 3);  // XCD chunk
  const int bm = bswz / nblk, bn = bswz % nblk;
  const int t = threadIdx.x;
  const int lane = t & 63, wave = t >> 6;
  const int c = lane & 15, g = lane >> 4;
  const int wm = (wave >> 1) * 64, wn = (wave & 1) * 64;
  const int srow = t >> 2, schunk = t & 3;           // staging map: 64B rows
  const bf16* Ab = A  + (size_t)(bm*128) * DIM;
  const bf16* Bb = Bt + (size_t)(bn*128) * DIM;
  f32x4 acc[4][4] = {};
  for (int k0 = 0; k0 < DIM; k0 += 32) {
    __syncthreads();
#pragma unroll
    for (int i = 0; i < 2; ++i) {
      GLD16(Ab + (size_t)(i*64 + srow)*DIM + k0 + schunk*8,
            (char*)Als + i*4096 + t*16);
      GLD16(Bb + (size_t)(i*64 + srow)*DIM + k0 + schunk*8,
            (char*)Bls + i*4096 + t*16);
    }
    __syncthreads();
    bf16x8 a[4], b[4];
#pragma unroll
    for (int m = 0; m < 4; ++m)
      a[m] = *(const bf16x8*)&Als[(wm + m*16 + c)*32 + g*8];
#pragma unroll
    for (int n = 0; n < 4; ++n)
      b[n] = *(const bf16x8*)&Bls[(wn + n*16 + c)*32 + g*8];
#pragma unroll
    for (int m = 0; m < 4; ++m)
#pragma unroll
      for (int n = 0; n < 4; ++n)
        acc[m][n] = __builtin_amdgcn_mfma_f32_16x16x32_bf16(a[m], b[n], acc[m][n], 0, 0, 0);
  }
  const int cb = bn*128 + wn, rb = bm*128 + wm;
  if (MODE == 0) {
    const int which = (bn*128) >> 10;                 // 0=Q 1=K 2=V
    if (which < 2) {
      bf16* dst = which == 0 ? Qb : Kb;
#pragma unroll
      for (int n = 0; n < 4; ++n) {
        const int colg = cb + n*16 + c;
        const int h = (colg >> 6) & 15, d = colg & 63;
        const size_t hd = (size_t)h * (SEQ*HDIM) + d;
#pragma unroll
        for (int m = 0; m < 4; ++m)
#pragma unroll
          for (int r = 0; r < 4; ++r) {
            const int row = rb + m*16 + 4*g + r;
            const int bb = row >> 11, nt = row & 2047;
            dst[(size_t)bb * (NHEADS*SEQ*HDIM) + hd + (size_t)nt * HDIM] = (bf16)acc[m][n][r];
          }
      }
    } else {
      // V transposed: Vt[b][h][d][n] ; 4 consecutive tokens -> bf16x4 store
#pragma unroll
      for (int n = 0; n < 4; ++n) {
        const int colg = cb + n*16 + c;
        const int h = (colg >> 6) & 15, d = colg & 63;
#pragma unroll
        for (int m = 0; m < 4; ++m) {
          const int row0 = rb + m*16 + 4*g;
          const int bb = row0 >> 11, nt = row0 & 2047;
          bf16x4 pk;
          pk[0] = (bf16)acc[m][n][0]; pk[1] = (bf16)acc[m][n][1];
          pk[2] = (bf16)acc[m][n][2]; pk[3] = (bf16)acc[m][n][3];
          *(bf16x4*)(Vb + ((size_t)(bb*NHEADS + h)*HDIM + d)*SEQ + nt) = pk;
        }
      }
    }
  } else {
#pragma unroll
    for (int n = 0; n < 4; ++n) {
      const int col = cb + n*16 + c;
      const float bias = g2[col] * bp[col];
#pragma unroll
      for (int m = 0; m < 4; ++m)
#pragma unroll
        for (int r = 0; r < 4; ++r) {
          const int row = rb + m*16 + 4*g + r;
          outp[(size_t)row * DIM + col] = acc[m][n][r] + bias;
        }
    }
  }
}

// ---------------------------------------------------------------- attention
// grid 512 = (B*H=64) x (N/256=8), XCD-chunked. 8 waves x 32 q-rows = 256 q.
// K/V double-buffered (2-phase prefetch: STAGE(t+1) issued before compute(t),
// ONE barrier per tile drains it). Swapped QK^T (S^T = mfma(K,Q)): each lane
// holds 4 consecutive kv of q-row (m*16+c) -> per-lane softmax (no shuffles in
// common path), packed b64 P-stores. l via ones-row MFMA (O^T row 64).
__global__ __launch_bounds__(512, 4) void k_attn(const bf16* __restrict__ Q,
                                                 const bf16* __restrict__ K,
                                                 const bf16* __restrict__ Vt,
                                                 bf16* __restrict__ O) {
  __shared__ __align__(16) char Kls[2][KVB*128];     // 16 KB
  __shared__ __align__(16) char Vls[2][KVB*128];     // 16 KB
  __shared__ __align__(16) char Ones[16*128];        //  2 KB
  __shared__ __align__(16) char Pls[8][32*PSTR_B];   // 36 KB
  const int b0 = blockIdx.x;
  const int bid = (b0 & 7) * 64 + (b0 >> 3);         // XCD chunk (512/8=64)
  const int qt = bid & 7, bh = bid >> 3;
  const int t = threadIdx.x, wave = t >> 6, lane = t & 63;
  const int c = lane & 15, g = lane >> 4;
  const int csw = (c & 7) << 4;                      // K/V read swizzle
  char* Pw = Pls[wave];
  const bf16* Qp = Q + ((size_t)bh * SEQ + qt*256) * HDIM;
  const bf16* Kp = K + (size_t)bh * SEQ * HDIM;
  const bf16* Vh = Vt + (size_t)bh * HDIM * SEQ;     // [d][n]
  // Ones block: V^T row 64 = 1.0 (l-row), rows 65..79 = 0. 2048B/512thr = 4B.
  {
    unsigned fill = (t*4 < 128) ? 0x3F803F80u : 0u;  // two bf16(1.0)
    *(unsigned*)(Ones + t*4) = fill;
  }
  // Q fragments (B-operand of swapped QK^T: col=lane&15->q, k=8g+j->d)
  bf16x8 qf[2][2];
#pragma unroll
  for (int m = 0; m < 2; ++m)
#pragma unroll
    for (int kk = 0; kk < 2; ++kk)
      qf[m][kk] = *(const bf16x8*)(Qp + (size_t)(wave*32 + m*16 + c)*HDIM + kk*32 + g*8);
  f32x4 oacc[2][5] = {};                             // df=4 holds l (row 64)
  float rm[2] = {-1e30f, -1e30f};                    // per-lane: q = m*16+c

  // staging map: 512 threads x 16B = one 64x64 bf16 tile per round
  const int srow = t >> 3, scbk = t & 7;
#define STAGE(buf, kv0) { \
  GLD16(Kp + (size_t)((kv0) + srow)*HDIM + 8*(scbk ^ (srow & 7)), Kls[buf] + t*16); \
  GLD16(Vh + (size_t)srow*SEQ + (kv0) + 8*(scbk ^ (srow & 7)), Vls[buf] + t*16); }

  STAGE(0, 0);
  __syncthreads();                                   // drain prologue stage
  int cur = 0;
  for (int tile = 0; tile < NT; ++tile) {
    if (tile + 1 < NT) STAGE(cur ^ 1, (tile + 1)*KVB);  // prefetch next
    // S^T = K Q^T : s2[n][m] rows kv=n*16+4g+r, cols q=m*16+c
    f32x4 s2[4][2] = {};
#pragma unroll
    for (int kk = 0; kk < 2; ++kk)
#pragma unroll
      for (int n = 0; n < 4; ++n) {
        const bf16x8 kb = *(const bf16x8*)(Kls[cur] + (n*16 + c)*128 + ((kk*64 + 16*g) ^ csw));
#pragma unroll
        for (int m = 0; m < 2; ++m)
          s2[n][m] = __builtin_amdgcn_mfma_f32_16x16x32_bf16(kb, qf[m][kk], s2[n][m], 0, 0, 0);
      }
    // per-lane softmax: lane owns 16 kv-samples of its q-row per m
    float pm[2];
    bool allok = true;
#pragma unroll
    for (int m = 0; m < 2; ++m) {
      float v = s2[0][m][0];
#pragma unroll
      for (int n = 0; n < 4; ++n)
#pragma unroll
        for (int r = 0; r < 4; ++r) v = fmaxf(v, s2[n][m][r]);
      pm[m] = v;
      allok = allok && (v <= rm[m] + DEFER_THR);
    }
    if (tile == 0 || !__all((int)allok)) {           // rare full reduce
#pragma unroll
      for (int m = 0; m < 2; ++m) {
        float v = pm[m];
        v = fmaxf(v, __shfl_xor(v, 16));             // cross-g (same c): full row
        v = fmaxf(v, __shfl_xor(v, 32));
        const float mnew = fmaxf(rm[m], v);
        const float alpha = exp2g(rm[m] - mnew);
        rm[m] = mnew;
#pragma unroll
        for (int df = 0; df < 5; ++df) {
          oacc[m][df][0] *= alpha; oacc[m][df][1] *= alpha;
          oacc[m][df][2] *= alpha; oacc[m][df][3] *= alpha;
        }
      }
    }
    // P = exp2(S^T - rm): 4 consecutive kv per (m,n) -> packed 8B store
#pragma unroll
    for (int m = 0; m < 2; ++m)
#pragma unroll
      for (int n = 0; n < 4; ++n) {
        bf16x4 pk;
#pragma unroll
        for (int r = 0; r < 4; ++r) pk[r] = (bf16)exp2g(s2[n][m][r] - rm[m]);
        *(bf16x4*)(Pw + (m*16 + c)*PSTR_B + n*32 + g*8) = pk;
      }
    // O^T += V^T P^T (df=4: ones-row -> l). All operands ds_read_b128.
#pragma unroll
    for (int kf = 0; kf < 2; ++kf) {
      bf16x8 pbm[2];
#pragma unroll
      for (int m = 0; m < 2; ++m)
        pbm[m] = *(const bf16x8*)(Pw + (m*16 + c)*PSTR_B + kf*64 + 16*g);
#pragma unroll
      for (int df = 0; df < 5; ++df) {
        const bf16x8 va = (df < 4)
          ? *(const bf16x8*)(Vls[cur] + (df*16 + c)*128 + ((kf*64 + 16*g) ^ csw))
          : *(const bf16x8*)(Ones + c*128 + ((kf*64 + 16*g) ^ csw));
#pragma unroll
        for (int m = 0; m < 2; ++m)
          oacc[m][df] = __builtin_amdgcn_mfma_f32_16x16x32_bf16(va, pbm[m], oacc[m][df], 0, 0, 0);
      }
    }
    __syncthreads();                                 // drain prefetch + buf reuse
    cur ^= 1;
  }
#undef STAGE
  // epilogue: O^T[d][q] -> O[b][q][h*64+d] bf16. l at row 64 = (g=0,r=0) lanes.
  const int b = bh >> 4, h = bh & 15;
#pragma unroll
  for (int m = 0; m < 2; ++m) {
    const float lq = __shfl(oacc[m][4][0], c, 64);   // from lane (g=0, c)
    const float inv = 1.0f / lq;
    const int qg = qt*256 + wave*32 + m*16 + c;
    bf16* orow = O + ((size_t)b*SEQ + qg)*DIM + h*HDIM;
#pragma unroll
    for (int df = 0; df < 4; ++df)
#pragma unroll
      for (int r = 0; r < 4; ++r)
        orow[df*16 + 4*g + r] = (bf16)(oacc[m][df][r] * inv);
  }
}

// ---------------------------------------------------------------- launch
extern "C" void kernel_launch(void* const* d_in, const int* in_sizes, int n_in,
                              void* d_out, int out_size, void* d_ws, size_t ws_size,
                              hipStream_t stream) {
  const float* x    = (const float*)d_in[0];
  const float* Wqkv = (const float*)d_in[1];
  const float* g1   = (const float*)d_in[2];
  const float* Wp   = (const float*)d_in[3];
  const float* bp   = (const float*)d_in[4];
  const float* g2   = (const float*)d_in[5];
  float* out = (float*)d_out;
  char* ws = (char*)d_ws;
  bf16* xb  = (bf16*)ws;                       // 16 MiB [8192][1024]; reused as O
  bf16* Wqt = (bf16*)(ws + (16u<<20));         //  6 MiB [3072][1024]
  bf16* Wpt = (bf16*)(ws + (22u<<20));         //  2 MiB [1024][1024]
  bf16* Qb  = (bf16*)(ws + (24u<<20));         // 16 MiB [b][h][n][d]
  bf16* Kb  = (bf16*)(ws + (40u<<20));         // 16 MiB [b][h][n][d]
  bf16* Vb  = (bf16*)(ws + (56u<<20));         // 16 MiB [b][h][d][n]  (transposed)

  k_cvt_x<<<(MTOT*DIM)/1024, 256, 0, stream>>>(x, xb);
  k_prep_w<<<dim3(96, 32), dim3(32, 8), 0, stream>>>(Wqkv, g1, Wqt, 3*DIM, 1);
  k_prep_w<<<dim3(32, 32), dim3(32, 8), 0, stream>>>(Wp, g2, Wpt, DIM, 0);
  k_gemm<0><<<64*24, 256, 0, stream>>>(xb, Wqt, 24, nullptr, nullptr, nullptr, Qb, Kb, Vb);
  k_attn<<<512, 512, 0, stream>>>(Qb, Kb, Vb, xb);
  k_gemm<1><<<64*8, 256, 0, stream>>>(xb, Wpt, 8, out, g2, bp, nullptr, nullptr, nullptr);
}